// Round 1
// baseline (63.914 us; speedup 1.0000x reference)
//
#include <hip/hip_runtime.h>
#include <hip/hip_bf16.h>
#include <math.h>

#define QN 8192
#define CN 64
#define SHOT 5
#define DN 512

#define WAVES 4
#define TQ 8
#define QPB (WAVES * TQ)      // 32 queries per block
#define DCHUNK 256
#define PSTRIDE 65            // pad: bank = (d + c) % 32 -> 2-way (free)

// --- proto kernel: proto[c][d] = mean over SHOT of y[c][s][d] ---
__global__ void proto_kernel(const float* __restrict__ y, float* __restrict__ proto) {
    int idx = blockIdx.x * blockDim.x + threadIdx.x;   // 0 .. C*D-1
    if (idx < CN * DN) {
        int c = idx >> 9;          // / 512
        int d = idx & (DN - 1);
        float s = 0.f;
#pragma unroll
        for (int sh = 0; sh < SHOT; ++sh)
            s += y[(c * SHOT + sh) * DN + d];
        proto[idx] = s * (1.0f / SHOT);
    }
}

// --- main kernel: lane = class, wave = 8 queries ---
__global__ __launch_bounds__(256, 2) void dist_softmax_kernel(
        const float* __restrict__ x,
        const float* __restrict__ proto,
        float* __restrict__ out) {
    __shared__ float plds[DCHUNK * PSTRIDE];   // [d][c] padded, 66,560 B

    const int tid  = threadIdx.x;
    const int lane = tid & 63;
    const int wave = __builtin_amdgcn_readfirstlane(tid >> 6);
    const int q0   = blockIdx.x * QPB + wave * TQ;

    float acc[TQ];
#pragma unroll
    for (int i = 0; i < TQ; ++i) acc[i] = 0.f;

    for (int d0 = 0; d0 < DN; d0 += DCHUNK) {
        // stage proto[c][d0..d0+DCHUNK) -> plds[dd][c]  (coalesced read, conflict-free write)
        for (int i = tid; i < CN * DCHUNK; i += 256) {
            int c  = i >> 8;              // / DCHUNK
            int dd = i & (DCHUNK - 1);
            plds[dd * PSTRIDE + c] = proto[c * DN + d0 + dd];
        }
        __syncthreads();

        const float* xbase = x + q0 * DN + d0;
#pragma unroll 2
        for (int dd = 0; dd < DCHUNK; dd += 4) {
            float p0 = plds[(dd + 0) * PSTRIDE + lane];
            float p1 = plds[(dd + 1) * PSTRIDE + lane];
            float p2 = plds[(dd + 2) * PSTRIDE + lane];
            float p3 = plds[(dd + 3) * PSTRIDE + lane];
#pragma unroll
            for (int qi = 0; qi < TQ; ++qi) {
                float4 xv = *(const float4*)(xbase + qi * DN + dd);
                acc[qi] += fabsf(xv.x - p0) + fabsf(xv.y - p1)
                         + fabsf(xv.z - p2) + fabsf(xv.w - p3);
            }
        }
        __syncthreads();
    }

    // softmax over classes (= over lanes) for each of this wave's TQ queries
#pragma unroll
    for (int qi = 0; qi < TQ; ++qi) {
        float nd = -acc[qi];
        float m = nd;
#pragma unroll
        for (int off = 32; off; off >>= 1)
            m = fmaxf(m, __shfl_xor(m, off, 64));
        float e = __expf(nd - m);
        float s = e;
#pragma unroll
        for (int off = 32; off; off >>= 1)
            s += __shfl_xor(s, off, 64);
        out[(q0 + qi) * CN + lane] = e / s;
    }
}

extern "C" void kernel_launch(void* const* d_in, const int* in_sizes, int n_in,
                              void* d_out, int out_size, void* d_ws, size_t ws_size,
                              hipStream_t stream) {
    const float* x = (const float*)d_in[0];   // [8192, 512]
    const float* y = (const float*)d_in[1];   // [64, 5, 512]
    float* out     = (float*)d_out;           // [8192, 64]
    float* proto   = (float*)d_ws;            // [64, 512] = 131072 B scratch

    proto_kernel<<<(CN * DN + 255) / 256, 256, 0, stream>>>(y, proto);
    dist_softmax_kernel<<<QN / QPB, 256, 0, stream>>>(x, proto, out);
}

// Round 2
// 34.062 us; speedup vs baseline: 1.8764x; 1.8764x over previous
//
#include <hip/hip_runtime.h>
#include <hip/hip_bf16.h>
#include <math.h>

#define QN 8192
#define CN 64
#define SHOT 5
#define DN 512

#define THREADS 512
#define WAVES 8
#define TQ 2
#define QPB (WAVES * TQ)      // 16 queries per block -> grid 512 = 2 blocks/CU
#define DCHUNK 128
#define F4 (DCHUNK / 4)       // 32 float4 per class-row chunk

// --- proto kernel: proto[c][d] = mean over SHOT of y[c][s][d] ---
__global__ void proto_kernel(const float* __restrict__ y, float* __restrict__ proto) {
    int idx = blockIdx.x * blockDim.x + threadIdx.x;   // 0 .. C*D-1
    if (idx < CN * DN) {
        int c = idx >> 9;          // / 512
        int d = idx & (DN - 1);
        float s = 0.f;
#pragma unroll
        for (int sh = 0; sh < SHOT; ++sh)
            s += y[(c * SHOT + sh) * DN + d];
        proto[idx] = s * (1.0f / SHOT);
    }
}

// --- main kernel: lane = class, wave = TQ queries, XOR-swizzled proto in LDS ---
__global__ __launch_bounds__(THREADS, 4) void dist_softmax_kernel(
        const float* __restrict__ x,
        const float* __restrict__ proto,
        float* __restrict__ out) {
    __shared__ float4 plds[CN * F4];   // 64 x 32 float4 = 32 KiB, XOR-swizzled

    const int tid  = threadIdx.x;
    const int lane = tid & 63;
    const int wave = __builtin_amdgcn_readfirstlane(tid >> 6);
    const int q0   = blockIdx.x * QPB + wave * TQ;

    const float4* proto4 = (const float4*)proto;

    float acc0 = 0.f, acc1 = 0.f;

    for (int d0 = 0; d0 < DN; d0 += DCHUNK) {
        const int f0 = d0 >> 2;
        // stage proto[c][d0..d0+128) -> plds, swizzled. 2048 float4 / 512 thr = 4 each.
        // reads: 32 consecutive lanes read 512B contiguous (coalesced)
        // writes: offset16B%8 = (f^(c&7))%8 spans all banks (conflict-free)
#pragma unroll
        for (int k = 0; k < (CN * F4) / THREADS; ++k) {
            int i = tid + k * THREADS;
            int c = i >> 5;            // / F4
            int f = i & (F4 - 1);
            plds[c * F4 + (f ^ (c & 7))] = proto4[c * (DN / 4) + f0 + f];
        }
        __syncthreads();

        const float* xb = x + q0 * DN + d0;   // wave-uniform -> s_load broadcasts
#pragma unroll 4
        for (int f = 0; f < F4; ++f) {
            float4 p = plds[lane * F4 + (f ^ (lane & 7))];
            float4 a = *(const float4*)(xb + f * 4);
            float4 b = *(const float4*)(xb + DN + f * 4);
            acc0 += fabsf(a.x - p.x) + fabsf(a.y - p.y)
                  + fabsf(a.z - p.z) + fabsf(a.w - p.w);
            acc1 += fabsf(b.x - p.x) + fabsf(b.y - p.y)
                  + fabsf(b.z - p.z) + fabsf(b.w - p.w);
        }
        __syncthreads();
    }

    // softmax over classes (= lanes) for the wave's 2 queries
    float accs[TQ] = {acc0, acc1};
#pragma unroll
    for (int qi = 0; qi < TQ; ++qi) {
        float nd = -accs[qi];
        float m = nd;
#pragma unroll
        for (int off = 32; off; off >>= 1)
            m = fmaxf(m, __shfl_xor(m, off, 64));
        float e = __expf(nd - m);
        float s = e;
#pragma unroll
        for (int off = 32; off; off >>= 1)
            s += __shfl_xor(s, off, 64);
        out[(q0 + qi) * CN + lane] = e / s;
    }
}

extern "C" void kernel_launch(void* const* d_in, const int* in_sizes, int n_in,
                              void* d_out, int out_size, void* d_ws, size_t ws_size,
                              hipStream_t stream) {
    const float* x = (const float*)d_in[0];   // [8192, 512]
    const float* y = (const float*)d_in[1];   // [64, 5, 512]
    float* out     = (float*)d_out;           // [8192, 64]
    float* proto   = (float*)d_ws;            // [64, 512] scratch

    proto_kernel<<<(CN * DN + 255) / 256, 256, 0, stream>>>(y, proto);
    dist_softmax_kernel<<<QN / QPB, THREADS, 0, stream>>>(x, proto, out);
}